// Round 5
// baseline (156.402 us; speedup 1.0000x reference)
//
#include <hip/hip_runtime.h>
#include <hip/hip_bf16.h>

// SpanV2 combo-table decomposition, round 5.
// spans (start,end,width) all in [0,10] -> logits separable into
// relu(PS[b][s][k] + PE[b][e][k] + PW[w][k]) @ W2, only 16*1331 distinct rows.
// prep:      W1T[n][k<1536] bf16 (LDS-tiled transpose), W2T[32][768] bf16,
//            PW[v][n] = wemb[v]@W1c fp32 (k=150 vector loop).
// precompute: barrier-free/LDS-free MFMA: A-frags direct from hs (k-contig),
//            B-frags single uint4 from W1T. PS (+b1) and PE fp32.
// combo:     split-K x2, barrier-free k-loop: PS/PE/PW staged fp32 in LDS once,
//            h built directly in A-frag registers, W2T B-frags from global.
//            Each z writes its own LT partial (no atomics).
// gather:    out = LT0 + LT1 + b2.

#define NB 16
#define NH 768
#define NV 11
#define NL 25
#define NCOMBO 1331
#define KPAD 1536

typedef __attribute__((ext_vector_type(8))) short frag8;
typedef __attribute__((ext_vector_type(4))) float f32x4;

__device__ __forceinline__ unsigned short f2bf(float f) {
    unsigned int u = __float_as_uint(f);
    u = (u + 0x7FFFu + ((u >> 16) & 1u)) >> 16;  // RNE
    return (unsigned short)u;
}
__device__ __forceinline__ unsigned int pack2(float lo, float hi) {
    return (unsigned int)f2bf(lo) | ((unsigned int)f2bf(hi) << 16);
}

// ---------------- Kernel 0: prep (W1T transpose, W2T, PW) ----------------
#define TST 68   // fp32 tile stride (64+4): 272 B rows, 16B-aligned, 2-way banks
__global__ __launch_bounds__(256) void prep_kernel(
    const float* __restrict__ W1, const float* __restrict__ W2,
    const float* __restrict__ wemb,
    unsigned short* __restrict__ W1T, unsigned short* __restrict__ W2T,
    float* __restrict__ PW)
{
    __shared__ float T[64 * TST];
    const int x = blockIdx.x, y = blockIdx.y, tid = threadIdx.x;

    if (x < 24) {
        const int k0 = x * 64, n0 = y * 64;
        #pragma unroll
        for (int p = 0; p < 4; ++p) {
            int kl = (tid >> 4) + p * 16;
            int n4 = tid & 15;
            *(float4*)&T[kl * TST + n4 * 4] =
                *(const float4*)&W1[(size_t)(k0 + kl) * NH + n0 + n4 * 4];
        }
        __syncthreads();
        const int n = tid >> 2, kg = tid & 3;
        unsigned int o[8];
        #pragma unroll
        for (int i = 0; i < 8; ++i) {
            float a = T[(kg * 16 + 2 * i) * TST + n];
            float b = T[(kg * 16 + 2 * i + 1) * TST + n];
            o[i] = pack2(a, b);
        }
        unsigned short* dst = &W1T[(size_t)(n0 + n) * KPAD + k0 + kg * 16];
        *(uint4*)dst = make_uint4(o[0], o[1], o[2], o[3]);
        *(uint4*)(dst + 8) = make_uint4(o[4], o[5], o[6], o[7]);
    } else if (x == 24) {
        // W2T[n2][k] bf16, k-slice [y*64, y*64+64)
        const int n2 = tid & 31, kq = tid >> 5;
        const int k = y * 64 + kq * 8;
        unsigned int o[4];
        #pragma unroll
        for (int i = 0; i < 4; ++i) {
            float a = (n2 < NL) ? W2[(size_t)(k + 2 * i) * NL + n2] : 0.0f;
            float b = (n2 < NL) ? W2[(size_t)(k + 2 * i + 1) * NL + n2] : 0.0f;
            o[i] = pack2(a, b);
        }
        *(uint4*)&W2T[(size_t)n2 * NH + k] = make_uint4(o[0], o[1], o[2], o[3]);
    } else {
        // PW[v][n] = sum_{k<150} wemb[v][k] * W1[1536+k][n], n-slice y*64
        const int n = y * 64 + (tid & 63);
        const int vg = tid >> 6;
        float acc[3] = {0.f, 0.f, 0.f};
        for (int k = 0; k < 150; k += 2) {
            float w1a = W1[(size_t)(1536 + k) * NH + n];
            float w1b = W1[(size_t)(1537 + k) * NH + n];
            #pragma unroll
            for (int j = 0; j < 3; ++j) {
                int v = vg + j * 4; int vs = (v < NV) ? v : 0;
                acc[j] += wemb[vs * 150 + k] * w1a + wemb[vs * 150 + k + 1] * w1b;
            }
        }
        #pragma unroll
        for (int j = 0; j < 3; ++j) {
            int v = vg + j * 4;
            if (v < NV) PW[(size_t)v * NH + n] = acc[j];
        }
    }
}

// ---------------- Kernel 1: precompute PS/PE (barrier-free MFMA) ----------
// grid (6, 6): x = 128-col n-tile, y<3: part0 (PS) m-group, y>=3: part1 (PE).
__global__ __launch_bounds__(256) void precompute_kernel(
    const float* __restrict__ hs, const unsigned short* __restrict__ W1T,
    const float* __restrict__ b1,
    float* __restrict__ PS, float* __restrict__ PE)
{
    const int tid = threadIdx.x;
    const int wave = tid >> 6, lane = tid & 63, q = lane >> 4, ln = lane & 15;
    const int n0 = blockIdx.x * 128;
    const int y = blockIdx.y;
    const int part = (y >= 3);
    const int mbase = (part ? y - 3 : y) * 64;
    const int koff = part * NH;
    const int ncol = n0 + wave * 32;

    const float* rowp[4]; bool valid[4];
    #pragma unroll
    for (int mt = 0; mt < 4; ++mt) {
        int m = mbase + mt * 16 + ln;
        int b = m / 12, v = m - 12 * b;
        valid[mt] = (v < NV);
        rowp[mt] = hs + ((size_t)(b * 512 + v)) * NH;
    }

    f32x4 acc[4][2];
    #pragma unroll
    for (int mt = 0; mt < 4; ++mt)
        #pragma unroll
        for (int nt = 0; nt < 2; ++nt)
            #pragma unroll
            for (int r = 0; r < 4; ++r) acc[mt][nt][r] = 0.0f;

    #pragma unroll 2
    for (int ch = 0; ch < 12; ++ch) {
        const int k0 = ch * 64;
        frag8 af[2][4];
        #pragma unroll
        for (int kt = 0; kt < 2; ++kt)
            #pragma unroll
            for (int mt = 0; mt < 4; ++mt) {
                union { uint4 u; frag8 f; } cv;
                if (valid[mt]) {
                    const float* p = rowp[mt] + k0 + kt * 32 + q * 8;
                    float4 a = *(const float4*)p;
                    float4 b = *(const float4*)(p + 4);
                    cv.u = make_uint4(pack2(a.x, a.y), pack2(a.z, a.w),
                                      pack2(b.x, b.y), pack2(b.z, b.w));
                } else cv.u = make_uint4(0, 0, 0, 0);
                af[kt][mt] = cv.f;
            }
        frag8 bfr[2][2];
        #pragma unroll
        for (int kt = 0; kt < 2; ++kt)
            #pragma unroll
            for (int nt = 0; nt < 2; ++nt)
                bfr[kt][nt] = *(const frag8*)&W1T[
                    (size_t)(ncol + nt * 16 + ln) * KPAD + koff + k0 + kt * 32 + q * 8];
        #pragma unroll
        for (int kt = 0; kt < 2; ++kt)
            #pragma unroll
            for (int mt = 0; mt < 4; ++mt)
                #pragma unroll
                for (int nt = 0; nt < 2; ++nt)
                    acc[mt][nt] = __builtin_amdgcn_mfma_f32_16x16x32_bf16(
                        af[kt][mt], bfr[kt][nt], acc[mt][nt], 0, 0, 0);
    }

    float* dst = part ? PE : PS;
    #pragma unroll
    for (int nt = 0; nt < 2; ++nt) {
        const int n = ncol + nt * 16 + ln;
        const float bb = part ? 0.0f : b1[n];
        #pragma unroll
        for (int mt = 0; mt < 4; ++mt)
            #pragma unroll
            for (int r = 0; r < 4; ++r) {
                int m = mbase + mt * 16 + q * 4 + r;
                int b = m / 12, v = m - 12 * b;
                if (v < NV)
                    dst[((size_t)(b * NV + v)) * NH + n] = acc[mt][nt][r] + bb;
            }
    }
}

// ---------------- Kernel 2: combo (split-K x2, barrier-free k-loop) -------
#define PFST 388   // fp32 row stride (384+4); 1552 B, 16B-aligned
__global__ __launch_bounds__(256) void combo_kernel(
    const float* __restrict__ PS, const float* __restrict__ PE,
    const float* __restrict__ PW, const unsigned short* __restrict__ W2T,
    float* __restrict__ LT)
{
    __shared__ float baseL[384];
    __shared__ float peL[NV * PFST];
    __shared__ float pwL[NV * PFST];

    const int tid = threadIdx.x;
    const int wave = tid >> 6, lane = tid & 63, q = lane >> 4, ln = lane & 15;
    const int b = blockIdx.x / NV, s = blockIdx.x - NV * b;
    const int kb = blockIdx.y * 384;

    const float* ps = PS + (size_t)(b * NV + s) * NH + kb;
    for (int i = tid; i < 96; i += 256)
        *(float4*)&baseL[i * 4] = *(const float4*)&ps[i * 4];
    for (int i = tid; i < NV * 96; i += 256) {
        int v = i / 96, j = i - 96 * v;
        *(float4*)&peL[v * PFST + j * 4] =
            *(const float4*)&PE[((size_t)(b * NV + v)) * NH + kb + j * 4];
        *(float4*)&pwL[v * PFST + j * 4] =
            *(const float4*)&PW[(size_t)v * NH + kb + j * 4];
    }

    int eIdx[2], wIdx[2];
    #pragma unroll
    for (int mtl = 0; mtl < 2; ++mtl) {
        int m = (wave * 2 + mtl) * 16 + ln;
        int me = (m < 121) ? m : 120;
        eIdx[mtl] = (me * 373) >> 12;          // me/11 for me<=120
        wIdx[mtl] = me - NV * eIdx[mtl];
    }

    f32x4 acc[2][2];
    #pragma unroll
    for (int a = 0; a < 2; ++a)
        #pragma unroll
        for (int c = 0; c < 2; ++c)
            #pragma unroll
            for (int r = 0; r < 4; ++r) acc[a][c][r] = 0.0f;

    __syncthreads();

    for (int ch = 0; ch < 6; ++ch) {
        #pragma unroll
        for (int kt = 0; kt < 2; ++kt) {
            const int kk = ch * 64 + kt * 32 + q * 8;
            float4 c0 = *(const float4*)&baseL[kk];
            float4 c1 = *(const float4*)&baseL[kk + 4];
            frag8 af[2];
            #pragma unroll
            for (int mtl = 0; mtl < 2; ++mtl) {
                const float* pe = &peL[eIdx[mtl] * PFST + kk];
                const float* pw = &pwL[wIdx[mtl] * PFST + kk];
                float4 p0 = *(const float4*)pe, p1 = *(const float4*)(pe + 4);
                float4 w0 = *(const float4*)pw, w1 = *(const float4*)(pw + 4);
                union { uint4 u; frag8 f; } cv;
                cv.u = make_uint4(
                    pack2(fmaxf(c0.x + p0.x + w0.x, 0.f), fmaxf(c0.y + p0.y + w0.y, 0.f)),
                    pack2(fmaxf(c0.z + p0.z + w0.z, 0.f), fmaxf(c0.w + p0.w + w0.w, 0.f)),
                    pack2(fmaxf(c1.x + p1.x + w1.x, 0.f), fmaxf(c1.y + p1.y + w1.y, 0.f)),
                    pack2(fmaxf(c1.z + p1.z + w1.z, 0.f), fmaxf(c1.w + p1.w + w1.w, 0.f)));
                af[mtl] = cv.f;
            }
            #pragma unroll
            for (int nt = 0; nt < 2; ++nt) {
                frag8 bf = *(const frag8*)&W2T[(size_t)(nt * 16 + ln) * NH + kb + kk];
                #pragma unroll
                for (int mtl = 0; mtl < 2; ++mtl)
                    acc[mtl][nt] = __builtin_amdgcn_mfma_f32_16x16x32_bf16(
                        af[mtl], bf, acc[mtl][nt], 0, 0, 0);
            }
        }
    }

    float* LTz = LT + (size_t)blockIdx.y * (NB * NCOMBO * NL);
    #pragma unroll
    for (int nt = 0; nt < 2; ++nt) {
        int n = nt * 16 + ln;
        if (n < NL) {
            #pragma unroll
            for (int mtl = 0; mtl < 2; ++mtl)
                #pragma unroll
                for (int r = 0; r < 4; ++r) {
                    int m = (wave * 2 + mtl) * 16 + q * 4 + r;
                    if (m < 121)
                        LTz[((size_t)b * NCOMBO + s * 121 + m) * NL + n] =
                            acc[mtl][nt][r];
                }
        }
    }
}

// ---------------- Kernel 3: gather ----------------
__global__ __launch_bounds__(256) void gather_kernel(
    const int* __restrict__ spans, const float* __restrict__ LT,
    const float* __restrict__ b2, float* __restrict__ out)
{
    const int idx = blockIdx.x * 256 + threadIdx.x;   // < 16*4096*25
    const int span = idx / NL;
    const int c = idx - span * NL;
    const int b = span >> 12;
    const int s = spans[span * 3 + 0];
    const int e = spans[span * 3 + 1];
    const int w = spans[span * 3 + 2];
    const size_t cidx = (size_t)(b * NCOMBO + s * 121 + e * NV + w) * NL + c;
    out[idx] = LT[cidx] + LT[(size_t)NB * NCOMBO * NL + cidx] + b2[c];
}

extern "C" void kernel_launch(void* const* d_in, const int* in_sizes, int n_in,
                              void* d_out, int out_size, void* d_ws, size_t ws_size,
                              hipStream_t stream) {
    const float* hs    = (const float*)d_in[0];
    const int*   spans = (const int*)d_in[1];
    const float* wemb  = (const float*)d_in[2];
    const float* W1    = (const float*)d_in[3];
    const float* b1    = (const float*)d_in[4];
    const float* W2    = (const float*)d_in[5];
    const float* b2    = (const float*)d_in[6];
    float* out = (float*)d_out;

    float* PS = (float*)d_ws;                         // 135168 f
    float* PE = PS + NB * NV * NH;                    // 135168 f
    float* PW = PE + NB * NV * NH;                    // 8448 f
    float* LT = PW + NV * NH;                         // 2 * 532400 f
    unsigned short* W1T = (unsigned short*)(LT + 2 * NB * NCOMBO * NL);  // 768*1536 sh
    unsigned short* W2T = W1T + NH * KPAD;            // 24576 sh
    // total ~7.8 MB

    prep_kernel<<<dim3(26, 12), dim3(256), 0, stream>>>(W1, W2, wemb, W1T, W2T, PW);
    precompute_kernel<<<dim3(6, 6), dim3(256), 0, stream>>>(hs, W1T, b1, PS, PE);
    combo_kernel<<<dim3(NB * NV, 2), dim3(256), 0, stream>>>(PS, PE, PW, W2T, LT);
    gather_kernel<<<dim3((NB * 4096 * NL) / 256), dim3(256), 0, stream>>>(spans, LT, b2, out);
}

// Round 6
// 119.171 us; speedup vs baseline: 1.3124x; 1.3124x over previous
//
#include <hip/hip_runtime.h>
#include <hip/hip_bf16.h>

// SpanV2 combo-table decomposition, round 6.
// Key change vs r5: ALL hot-kernel operands pre-packed into MFMA fragment
// order (16B per lane, fully coalesced): W1F/W2F/HSA. precompute is
// LDS-free, barrier-free, 1152 wave-jobs.

#define NB 16
#define NH 768
#define NV 11
#define NL 25
#define NCOMBO 1331

typedef __attribute__((ext_vector_type(8))) short frag8;
typedef __attribute__((ext_vector_type(4))) float f32x4;

__device__ __forceinline__ unsigned short f2bf(float f) {
    unsigned int u = __float_as_uint(f);
    u = (u + 0x7FFFu + ((u >> 16) & 1u)) >> 16;  // RNE
    return (unsigned short)u;
}
__device__ __forceinline__ unsigned int pack2(float lo, float hi) {
    return (unsigned int)f2bf(lo) | ((unsigned int)f2bf(hi) << 16);
}

// Fragment-ordered layouts (shorts):
//  W1F[nt(48)][kg(48)][ln(16)][q(4)][8]   nt: n-tile of W1 output col, kg: 32-k chunk over k=0..1535
//  W2F[kc(24)][nt(2)][ln(16)][q(4)][8]    kc: 32-k chunk over 768, n2 = nt*16+ln (pad 25->32)
//  HSA[mt(12)][kc(24)][ln(16)][q(4)][8]   m = mt*16+ln = b*12+v (v==11 -> 0 pad)

// ---------------- Kernel 0: prep ----------------
#define TST 68
__global__ __launch_bounds__(256) void prep_kernel(
    const float* __restrict__ hs, const float* __restrict__ W1,
    const float* __restrict__ W2, const float* __restrict__ wemb,
    unsigned short* __restrict__ W1F, unsigned short* __restrict__ W2F,
    unsigned short* __restrict__ HSA, float* __restrict__ PW)
{
    __shared__ float T[64 * TST];
    const int x = blockIdx.x, y = blockIdx.y, tid = threadIdx.x;

    if (x < 24) {
        // W1 transpose tile: k0=x*64 (kg = 2x,2x+1), n0=y*64 (nt = y*4..y*4+3)
        const int k0 = x * 64, n0 = y * 64;
        #pragma unroll
        for (int p = 0; p < 4; ++p) {
            int kl = (tid >> 4) + p * 16;
            int n4 = tid & 15;
            *(float4*)&T[kl * TST + n4 * 4] =
                *(const float4*)&W1[(size_t)(k0 + kl) * NH + n0 + n4 * 4];
        }
        __syncthreads();
        const int n = tid >> 2, kgl = tid & 3;      // n 0..63, kgl 0..3 (16-k groups)
        const int nt = y * 4 + (n >> 4), ln = n & 15;
        #pragma unroll
        for (int half = 0; half < 2; ++half) {
            const int kk = kgl * 16 + half * 8;     // 0..56
            unsigned int o[4];
            #pragma unroll
            for (int i = 0; i < 4; ++i) {
                float a = T[(kk + 2 * i) * TST + n];
                float b = T[(kk + 2 * i + 1) * TST + n];
                o[i] = pack2(a, b);
            }
            const int kg = x * 2 + (kk >> 5);
            const int q = (kk >> 3) & 3;
            *(uint4*)&W1F[((((size_t)nt * 48 + kg) * 16 + ln) * 4 + q) * 8] =
                make_uint4(o[0], o[1], o[2], o[3]);
        }
    } else if (x == 24) {
        // W2F: k-slice y*64 (kc = 2y, 2y+1)
        const int kcl = tid >> 7, nt = (tid >> 6) & 1, ln = (tid >> 2) & 15, q = tid & 3;
        const int n2 = nt * 16 + ln;
        const int k = y * 64 + kcl * 32 + q * 8;
        unsigned int o[4];
        #pragma unroll
        for (int i = 0; i < 4; ++i) {
            float a = (n2 < NL) ? W2[(size_t)(k + 2 * i) * NL + n2] : 0.0f;
            float b = (n2 < NL) ? W2[(size_t)(k + 2 * i + 1) * NL + n2] : 0.0f;
            o[i] = pack2(a, b);
        }
        *(uint4*)&W2F[((((size_t)(y * 2 + kcl)) * 2 + nt) * 16 + ln) * 32 + q * 8] =
            make_uint4(o[0], o[1], o[2], o[3]);
    } else if (x == 25) {
        // PW[v][n] = wemb[v] @ W1[1536:1686], n-slice y*64
        const int n = y * 64 + (tid & 63);
        const int vg = tid >> 6;
        float acc[3] = {0.f, 0.f, 0.f};
        for (int k = 0; k < 150; k += 2) {
            float w1a = W1[(size_t)(1536 + k) * NH + n];
            float w1b = W1[(size_t)(1537 + k) * NH + n];
            #pragma unroll
            for (int j = 0; j < 3; ++j) {
                int v = vg + j * 4; int vs = (v < NV) ? v : 0;
                acc[j] += wemb[vs * 150 + k] * w1a + wemb[vs * 150 + k + 1] * w1b;
            }
        }
        #pragma unroll
        for (int j = 0; j < 3; ++j) {
            int v = vg + j * 4;
            if (v < NV) PW[(size_t)v * NH + n] = acc[j];
        }
    } else {
        // HSA pack: mt = y; 24 kc x 64 frag-units, 6 per thread
        const int mt = y;
        #pragma unroll
        for (int it = 0; it < 6; ++it) {
            int u = it * 256 + tid;                 // 0..1535
            int kc = u >> 6, ln = (u >> 2) & 15, q = u & 3;
            int m = mt * 16 + ln;
            int b = m / 12, v = m - 12 * b;
            unsigned int o[4] = {0, 0, 0, 0};
            if (v < NV) {
                const float* p = hs + ((size_t)(b * 512 + v)) * NH + kc * 32 + q * 8;
                float4 a = *(const float4*)p;
                float4 c = *(const float4*)(p + 4);
                o[0] = pack2(a.x, a.y); o[1] = pack2(a.z, a.w);
                o[2] = pack2(c.x, c.y); o[3] = pack2(c.z, c.w);
            }
            *(uint4*)&HSA[((((size_t)mt * 24 + kc) * 16 + ln) * 4 + q) * 8] =
                make_uint4(o[0], o[1], o[2], o[3]);
        }
    }
}

// ---------------- Kernel 1: precompute PS/PE ----------------
// 1152 wave-jobs: (part 2) x (nt 48) x (mt 12). Barrier-free, LDS-free.
__global__ __launch_bounds__(256) void precompute_kernel(
    const unsigned short* __restrict__ HSA, const unsigned short* __restrict__ W1F,
    const float* __restrict__ b1,
    float* __restrict__ PS, float* __restrict__ PE)
{
    const int tid = threadIdx.x;
    const int wave = tid >> 6, lane = tid & 63, q = lane >> 4, ln = lane & 15;
    const int job = blockIdx.x * 4 + wave;          // 0..1151
    const int part = job >= 576;
    const int j2 = job - part * 576;
    const int nt = j2 / 12;
    const int mt = j2 - nt * 12;

    const unsigned short* aP = HSA + (size_t)mt * 24 * 512 + ln * 32 + q * 8;
    const unsigned short* bP = W1F + ((size_t)nt * 48 + part * 24) * 512 + ln * 32 + q * 8;

    f32x4 acc;
    #pragma unroll
    for (int r = 0; r < 4; ++r) acc[r] = 0.0f;

    #pragma unroll 6
    for (int kc = 0; kc < 24; ++kc) {
        frag8 aF = *(const frag8*)(aP + kc * 512);
        frag8 bF = *(const frag8*)(bP + kc * 512);
        acc = __builtin_amdgcn_mfma_f32_16x16x32_bf16(aF, bF, acc, 0, 0, 0);
    }

    float* dst = part ? PE : PS;
    const int n = nt * 16 + ln;
    const float bb = part ? 0.0f : b1[n];
    #pragma unroll
    for (int r = 0; r < 4; ++r) {
        int m = mt * 16 + q * 4 + r;
        int b = m / 12, v = m - 12 * b;
        if (v < NV)
            dst[((size_t)(b * NV + v)) * NH + n] = acc[r] + bb;
    }
}

// ---------------- Kernel 2: combo (split-K x2, barrier-free k-loop) -------
#define PFST 388
__global__ __launch_bounds__(256) void combo_kernel(
    const float* __restrict__ PS, const float* __restrict__ PE,
    const float* __restrict__ PW, const unsigned short* __restrict__ W2F,
    float* __restrict__ LT)
{
    __shared__ float baseL[384];
    __shared__ float peL[NV * PFST];
    __shared__ float pwL[NV * PFST];

    const int tid = threadIdx.x;
    const int wave = tid >> 6, lane = tid & 63, q = lane >> 4, ln = lane & 15;
    const int b = blockIdx.x / NV, s = blockIdx.x - NV * b;
    const int kb = blockIdx.y * 384;

    const float* ps = PS + (size_t)(b * NV + s) * NH + kb;
    for (int i = tid; i < 96; i += 256)
        *(float4*)&baseL[i * 4] = *(const float4*)&ps[i * 4];
    for (int i = tid; i < NV * 96; i += 256) {
        int v = i / 96, j = i - 96 * v;
        *(float4*)&peL[v * PFST + j * 4] =
            *(const float4*)&PE[((size_t)(b * NV + v)) * NH + kb + j * 4];
        *(float4*)&pwL[v * PFST + j * 4] =
            *(const float4*)&PW[(size_t)v * NH + kb + j * 4];
    }

    int eIdx[2], wIdx[2];
    #pragma unroll
    for (int mtl = 0; mtl < 2; ++mtl) {
        int m = (wave * 2 + mtl) * 16 + ln;
        int me = (m < 121) ? m : 120;
        eIdx[mtl] = (me * 373) >> 12;
        wIdx[mtl] = me - NV * eIdx[mtl];
    }

    f32x4 acc[2][2];
    #pragma unroll
    for (int a = 0; a < 2; ++a)
        #pragma unroll
        for (int c = 0; c < 2; ++c)
            #pragma unroll
            for (int r = 0; r < 4; ++r) acc[a][c][r] = 0.0f;

    const unsigned short* w2p = W2F + ((size_t)blockIdx.y * 12) * 1024 + ln * 32 + q * 8;

    __syncthreads();

    for (int ch = 0; ch < 6; ++ch) {
        #pragma unroll
        for (int kt = 0; kt < 2; ++kt) {
            const int kk = ch * 64 + kt * 32 + q * 8;
            float4 c0 = *(const float4*)&baseL[kk];
            float4 c1 = *(const float4*)&baseL[kk + 4];
            frag8 af[2];
            #pragma unroll
            for (int mtl = 0; mtl < 2; ++mtl) {
                const float* pe = &peL[eIdx[mtl] * PFST + kk];
                const float* pw = &pwL[wIdx[mtl] * PFST + kk];
                float4 p0 = *(const float4*)pe, p1 = *(const float4*)(pe + 4);
                float4 w0 = *(const float4*)pw, w1 = *(const float4*)(pw + 4);
                union { uint4 u; frag8 f; } cv;
                cv.u = make_uint4(
                    pack2(fmaxf(c0.x + p0.x + w0.x, 0.f), fmaxf(c0.y + p0.y + w0.y, 0.f)),
                    pack2(fmaxf(c0.z + p0.z + w0.z, 0.f), fmaxf(c0.w + p0.w + w0.w, 0.f)),
                    pack2(fmaxf(c1.x + p1.x + w1.x, 0.f), fmaxf(c1.y + p1.y + w1.y, 0.f)),
                    pack2(fmaxf(c1.z + p1.z + w1.z, 0.f), fmaxf(c1.w + p1.w + w1.w, 0.f)));
                af[mtl] = cv.f;
            }
            #pragma unroll
            for (int nt = 0; nt < 2; ++nt) {
                frag8 bf = *(const frag8*)(w2p + ((ch * 2 + kt) * 2 + nt) * 512);
                #pragma unroll
                for (int mtl = 0; mtl < 2; ++mtl)
                    acc[mtl][nt] = __builtin_amdgcn_mfma_f32_16x16x32_bf16(
                        af[mtl], bf, acc[mtl][nt], 0, 0, 0);
            }
        }
    }

    float* LTz = LT + (size_t)blockIdx.y * (NB * NCOMBO * NL);
    #pragma unroll
    for (int nt = 0; nt < 2; ++nt) {
        int n = nt * 16 + ln;
        if (n < NL) {
            #pragma unroll
            for (int mtl = 0; mtl < 2; ++mtl)
                #pragma unroll
                for (int r = 0; r < 4; ++r) {
                    int m = (wave * 2 + mtl) * 16 + q * 4 + r;
                    if (m < 121)
                        LTz[((size_t)b * NCOMBO + s * 121 + m) * NL + n] =
                            acc[mtl][nt][r];
                }
        }
    }
}

// ---------------- Kernel 3: gather ----------------
__global__ __launch_bounds__(256) void gather_kernel(
    const int* __restrict__ spans, const float* __restrict__ LT,
    const float* __restrict__ b2, float* __restrict__ out)
{
    const int idx = blockIdx.x * 256 + threadIdx.x;
    const int span = idx / NL;
    const int c = idx - span * NL;
    const int b = span >> 12;
    const int s = spans[span * 3 + 0];
    const int e = spans[span * 3 + 1];
    const int w = spans[span * 3 + 2];
    const size_t cidx = (size_t)(b * NCOMBO + s * 121 + e * NV + w) * NL + c;
    out[idx] = LT[cidx] + LT[(size_t)NB * NCOMBO * NL + cidx] + b2[c];
}

extern "C" void kernel_launch(void* const* d_in, const int* in_sizes, int n_in,
                              void* d_out, int out_size, void* d_ws, size_t ws_size,
                              hipStream_t stream) {
    const float* hs    = (const float*)d_in[0];
    const int*   spans = (const int*)d_in[1];
    const float* wemb  = (const float*)d_in[2];
    const float* W1    = (const float*)d_in[3];
    const float* b1    = (const float*)d_in[4];
    const float* W2    = (const float*)d_in[5];
    const float* b2    = (const float*)d_in[6];
    float* out = (float*)d_out;

    float* PS = (float*)d_ws;                         // 135168 f
    float* PE = PS + NB * NV * NH;                    // 135168 f
    float* PW = PE + NB * NV * NH;                    // 8448 f
    float* LT = PW + NV * NH;                         // 2 * 532400 f
    unsigned short* W1F = (unsigned short*)(LT + 2 * NB * NCOMBO * NL);  // 48*48*512
    unsigned short* W2F = W1F + (size_t)48 * 48 * 512;                   // 24*2*512
    unsigned short* HSA = W2F + (size_t)24 * 2 * 512;                    // 12*24*512
    // total ~8.1 MB

    prep_kernel<<<dim3(27, 12), dim3(256), 0, stream>>>(
        hs, W1, W2, wemb, W1F, W2F, HSA, PW);
    precompute_kernel<<<dim3(288), dim3(256), 0, stream>>>(HSA, W1F, b1, PS, PE);
    combo_kernel<<<dim3(NB * NV, 2), dim3(256), 0, stream>>>(PS, PE, PW, W2F, LT);
    gather_kernel<<<dim3((NB * 4096 * NL) / 256), dim3(256), 0, stream>>>(
        spans, LT, b2, out);
}